// Round 13
// baseline (128.773 us; speedup 1.0000x reference)
//
#include <hip/hip_runtime.h>
#include <math.h>

#define NROW 4096
#define NDIM 128
#define KNN 10
#define LDSS 136  // bf16 LDS row stride (128 + 8 pad -> 2-way banks, 16B aligned)

typedef __bf16 bf16x8 __attribute__((ext_vector_type(8)));
typedef unsigned short u16x8 __attribute__((ext_vector_type(8)));
typedef unsigned short u16x4 __attribute__((ext_vector_type(4)));
typedef float f32x4 __attribute__((ext_vector_type(4)));

__device__ inline unsigned short f2bf(float f) {  // RTNE f32->bf16
    unsigned int u = __float_as_uint(f);
    u += 0x7FFFu + ((u >> 16) & 1u);
    return (unsigned short)(u >> 16);
}
__device__ inline float bf2f(unsigned short u) {
    return __uint_as_float((unsigned)u << 16);
}

// Dx intermediate (bf16) lives in the tail half of each f32 P-row slot:
//   bf16 row i = (__bf16*)(P + i*NROW + NROW/2), 4096 bf16 = 8 KB.

// ---- Kernel 1: gate, masked = x*gate (f32 + bf16 copies), r = rowsum(m^2) ---
__global__ __launch_bounds__(128) void k_mask(const float* __restrict__ x,
                                              const float* __restrict__ alpha,
                                              const float* __restrict__ noise,
                                              float* __restrict__ masked,
                                              unsigned short* __restrict__ mb,
                                              float* __restrict__ r) {
    int row = blockIdx.x;
    int c = threadIdx.x;
    float g = alpha[c] + 0.5f * noise[c] + 0.5f;
    g = fminf(fmaxf(g, 0.0f), 1.0f);
    float m = x[row * NDIM + c] * g;
    masked[row * NDIM + c] = m;
    mb[row * NDIM + c] = f2bf(m);   // bf16 source for the MFMA GEMM, written ONCE
    float v = m * m;
#pragma unroll
    for (int o = 32; o > 0; o >>= 1) v += __shfl_down(v, o, 64);
    __shared__ float partial[2];
    if ((c & 63) == 0) partial[c >> 6] = v;
    __syncthreads();
    if (c == 0) r[row] = partial[0] + partial[1];
}

// ------- Kernel 2: Dx = r_i + r_j - 2*M M^T via bf16 MFMA (round-4/R10 best) -
__global__ __launch_bounds__(256) void k_dx(const unsigned short* __restrict__ Mb,
                                            const float* __restrict__ r,
                                            float* __restrict__ P) {
    __shared__ __align__(16) __bf16 Asm[128 * LDSS];
    __shared__ __align__(16) __bf16 Bsm[128 * LDSS];
    int tid = threadIdx.x;
    int bx = blockIdx.x, by = blockIdx.y;

    {
        const unsigned short* Ap = Mb + (size_t)by * 128 * NDIM;
        const unsigned short* Bp = Mb + (size_t)bx * 128 * NDIM;
        int c = (tid & 15) * 8;
        int r0 = tid >> 4;
#pragma unroll
        for (int i = 0; i < 8; ++i) {
            int row = r0 + i * 16;
            *(uint4*)&Asm[row * LDSS + c] = *(const uint4*)(Ap + row * NDIM + c);
            *(uint4*)&Bsm[row * LDSS + c] = *(const uint4*)(Bp + row * NDIM + c);
        }
    }
    __syncthreads();

    int wave = tid >> 6, lane = tid & 63;
    int wr = wave >> 1, wc = wave & 1;
    int quad = lane >> 4, l15 = lane & 15;

    f32x4 acc[4][4];
#pragma unroll
    for (int i = 0; i < 4; ++i)
#pragma unroll
        for (int j = 0; j < 4; ++j) acc[i][j] = (f32x4)(0.0f);

#pragma unroll
    for (int kk = 0; kk < 128; kk += 32) {
        int ka = kk + quad * 8;
        bf16x8 af[4], bfr[4];
#pragma unroll
        for (int ti = 0; ti < 4; ++ti)
            af[ti] = *(const bf16x8*)&Asm[(wr * 64 + ti * 16 + l15) * LDSS + ka];
#pragma unroll
        for (int tj = 0; tj < 4; ++tj)
            bfr[tj] = *(const bf16x8*)&Bsm[(wc * 64 + tj * 16 + l15) * LDSS + ka];
#pragma unroll
        for (int ti = 0; ti < 4; ++ti)
#pragma unroll
            for (int tj = 0; tj < 4; ++tj)
                acc[ti][tj] = __builtin_amdgcn_mfma_f32_16x16x32_bf16(
                    af[ti], bfr[tj], acc[ti][tj], 0, 0, 0);
    }

    int gi_base = by * 128 + wr * 64;
    int gj_base = bx * 128 + wc * 64;
    float rrow[4][4], rcol[4];
#pragma unroll
    for (int ti = 0; ti < 4; ++ti)
#pragma unroll
        for (int rg = 0; rg < 4; ++rg)
            rrow[ti][rg] = r[gi_base + ti * 16 + quad * 4 + rg];
#pragma unroll
    for (int tj = 0; tj < 4; ++tj) rcol[tj] = r[gj_base + tj * 16 + l15];
#pragma unroll
    for (int ti = 0; ti < 4; ++ti)
#pragma unroll
        for (int rg = 0; rg < 4; ++rg) {
            int grow = gi_base + ti * 16 + quad * 4 + rg;
            __bf16* brow = (__bf16*)(P + (size_t)grow * NROW + NROW / 2);
#pragma unroll
            for (int tj = 0; tj < 4; ++tj) {
                int gcol = gj_base + tj * 16 + l15;
                float d = rrow[ti][rg] + rcol[tj] - 2.0f * acc[ti][tj][rg];
                ((unsigned short*)brow)[gcol] = f2bf(d);
            }
        }
}

// ------- Kernel 3: block-per-row top-10, LDS-tree merge (no shfl chains) -----
// 4096 blocks x 256 thr: each lane med3-inserts 16 elems into a sorted t[10],
// then an 8-step LDS binary tree merges the 256 lists (each step: read the
// partner's 10 floats, med3-insert = pure depth-1 VALU, barrier). Replaces the
// 10-round dependent ds_bpermute argmin chain AND doubles resident waves/CU.
__global__ __launch_bounds__(256) void k_knn(const float* __restrict__ P,
                                             float* __restrict__ knn) {
    int tid = threadIdx.x;
    int wave = tid >> 6, lane = tid & 63;
    int row = blockIdx.x;
    const unsigned short* drow =
        (const unsigned short*)(P + (size_t)row * NROW + NROW / 2) + wave * 1024;

    u16x8 v8[2];
#pragma unroll
    for (int c = 0; c < 2; ++c)
        v8[c] = *(const u16x8*)(drow + (c * 64 + lane) * 8);

    float t[KNN];
#pragma unroll
    for (int j = 0; j < KNN; ++j) t[j] = INFINITY;

#pragma unroll
    for (int c = 0; c < 2; ++c)
#pragma unroll
        for (int e = 0; e < 8; ++e) {
            float cv = bf2f(v8[c][e]);
            float t0n = fminf(t[0], cv);
#pragma unroll
            for (int j = KNN - 1; j >= 1; --j)
                t[j] = __builtin_amdgcn_fmed3f(cv, t[j - 1], t[j]);
            t[0] = t0n;
        }

    __shared__ float M[256][KNN + 1];  // stride 11 floats: conflict-free
#pragma unroll
    for (int j = 0; j < KNN; ++j) M[tid][j] = t[j];
    __syncthreads();

#pragma unroll
    for (int s = 128; s >= 1; s >>= 1) {
        if (tid < s) {
#pragma unroll
            for (int i = 0; i < KNN; ++i) {
                float cv = M[tid + s][i];
                float t0n = fminf(t[0], cv);
#pragma unroll
                for (int j = KNN - 1; j >= 1; --j)
                    t[j] = __builtin_amdgcn_fmed3f(cv, t[j - 1], t[j]);
                t[0] = t0n;
            }
            if (s > 1) {
#pragma unroll
                for (int j = 0; j < KNN; ++j) M[tid][j] = t[j];
            }
        }
        __syncthreads();
    }
    if (tid == 0) knn[row] = t[KNN - 1];
}

// -------- Kernel 4: median via radix select with DATA-ADAPTIVE shifts --------
__device__ inline unsigned fmap(float f) {
    unsigned b = __float_as_uint(f);
    return b ^ ((b >> 31) ? 0xFFFFFFFFu : 0x80000000u);
}
__device__ inline float funmap(unsigned u) {
    unsigned b = (u & 0x80000000u) ? (u ^ 0x80000000u) : ~u;
    return __uint_as_float(b);
}

__global__ __launch_bounds__(1024) void k_sigma(const float* __restrict__ knn,
                                                float* __restrict__ scale_out) {
    __shared__ unsigned keys[NROW];
    __shared__ unsigned hist[2048];
    __shared__ unsigned s_prefix, s_R;
    __shared__ unsigned red_lo[16], red_hi[16];
    __shared__ float red_f[16];
    __shared__ unsigned red_u[16];
    int tid = threadIdx.x;
    int lane = tid & 63, wid = tid >> 6;

    unsigned kmin = 0xFFFFFFFFu, kmax = 0u;
#pragma unroll
    for (int l = 0; l < 4; ++l) {
        unsigned k = fmap(knn[tid + l * 1024]);
        keys[tid + l * 1024] = k;
        kmin = min(kmin, k);
        kmax = max(kmax, k);
    }
#pragma unroll
    for (int o = 32; o > 0; o >>= 1) {
        kmin = min(kmin, (unsigned)__shfl_down(kmin, o, 64));
        kmax = max(kmax, (unsigned)__shfl_down(kmax, o, 64));
    }
    if (lane == 0) { red_lo[wid] = kmin; red_hi[wid] = kmax; }
    __syncthreads();
    kmin = red_lo[0]; kmax = red_hi[0];
#pragma unroll
    for (int w = 1; w < 16; ++w) {
        kmin = min(kmin, red_lo[w]);
        kmax = max(kmax, red_hi[w]);
    }

    unsigned xr = kmin ^ kmax;
    int B = (xr == 0u) ? 0 : (32 - __builtin_clz(xr));
    unsigned prefix0 = (B >= 32) ? 0u : (kmin >> B);

    if (tid == 0) { s_prefix = prefix0; s_R = 2047; }
    __syncthreads();

    int rem = B;
    for (int rd = 0; rd < 3; ++rd) {
        int w = rem > 11 ? 11 : rem;
        int sh = rem - w;
        unsigned nb = 1u << w;
        hist[tid] = 0;
        hist[tid + 1024] = 0;
        __syncthreads();
        unsigned prefix = s_prefix;
        unsigned R = s_R;
        int hsh = rem;
#pragma unroll
        for (int l = 0; l < 4; ++l) {
            unsigned k = keys[tid + l * 1024];
            bool match = (rd == 0) || ((k >> hsh) == prefix);
            if (match) atomicAdd(&hist[(k >> sh) & (nb - 1u)], 1u);
        }
        __syncthreads();
        if (tid < 64) {
            unsigned chunk = (nb >= 64u) ? (nb >> 6) : 1u;
            unsigned base = tid * chunk;
            unsigned lsum = 0;
            if (base < nb)
                for (unsigned i = 0; i < chunk; ++i) lsum += hist[base + i];
            unsigned pfx = lsum;
#pragma unroll
            for (int o = 1; o < 64; o <<= 1) {
                unsigned v = __shfl_up(pfx, o, 64);
                if (tid >= o) pfx += v;
            }
            unsigned excl = pfx - lsum;
            if (R >= excl && R < excl + lsum) {
                unsigned cum = excl;
                for (unsigned i = 0; i < chunk; ++i) {
                    unsigned h = hist[base + i];
                    if (R < cum + h) {
                        s_prefix = (prefix << w) | (base + i);
                        s_R = R - cum;
                        break;
                    }
                    cum += h;
                }
            }
        }
        __syncthreads();
        rem = sh;
    }

    unsigned mlk = s_prefix;
    unsigned cnt = 0, mng = 0xFFFFFFFFu;
#pragma unroll
    for (int l = 0; l < 4; ++l) {
        unsigned k = keys[tid + l * 1024];
        if (k <= mlk) cnt++;
        else mng = min(mng, k);
    }
#pragma unroll
    for (int o = 32; o > 0; o >>= 1) {
        cnt += __shfl_down(cnt, o, 64);
        mng = min(mng, (unsigned)__shfl_down(mng, o, 64));
    }
    if (lane == 0) { red_u[wid] = cnt; red_f[wid] = __uint_as_float(mng); }
    __syncthreads();
    if (tid == 0) {
        unsigned ctot = 0, m = 0xFFFFFFFFu;
        for (int w = 0; w < 16; ++w) {
            ctot += red_u[w];
            m = min(m, __float_as_uint(red_f[w]));
        }
        float ml = funmap(mlk);
        float mu = (ctot >= 2049u) ? ml : funmap(m);
        float sigma = 0.5f * (mu + ml);
        if (sigma < 1e-8f) sigma = 1.0f;
        scale_out[0] = -1.0f / (2.0f * sigma);
    }
}

// ------- Kernel 5: P-row = exp(bf16Dx*scale)/rowsum — LANE-COALESCED --------
__global__ __launch_bounds__(256) void k_norm(float* __restrict__ P,
                                              const float* __restrict__ scale_p) {
    int row = blockIdx.x, tid = threadIdx.x;
    float scale = scale_p[0];
    float* drow = P + (size_t)row * NROW;
    const unsigned short* brow = (const unsigned short*)(drow + NROW / 2);

    u16x4 a[4];
#pragma unroll
    for (int j = 0; j < 4; ++j)
        a[j] = *(const u16x4*)(brow + (j * 256 + tid) * 4);

    float v[16];
#pragma unroll
    for (int j = 0; j < 4; ++j)
#pragma unroll
        for (int e = 0; e < 4; ++e)
            v[j * 4 + e] = __expf(bf2f(a[j][e]) * scale);

    float sum = 0.0f;
#pragma unroll
    for (int e = 0; e < 16; ++e) sum += v[e];
#pragma unroll
    for (int o = 32; o > 0; o >>= 1) sum += __shfl_down(sum, o, 64);
    __shared__ float ps[4];
    int lane = tid & 63, wid = tid >> 6;
    if (lane == 0) ps[wid] = sum;
    __syncthreads();  // also orders all bf16 reads before the f32 overwrite
    float inv = 1.0f / (ps[0] + ps[1] + ps[2] + ps[3]);
#pragma unroll
    for (int j = 0; j < 4; ++j) {
        float4 o4;
        o4.x = v[j * 4 + 0] * inv;
        o4.y = v[j * 4 + 1] * inv;
        o4.z = v[j * 4 + 2] * inv;
        o4.w = v[j * 4 + 3] * inv;
        *(float4*)(drow + (j * 256 + tid) * 4) = o4;
    }
}

extern "C" void kernel_launch(void* const* d_in, const int* in_sizes, int n_in,
                              void* d_out, int out_size, void* d_ws, size_t ws_size,
                              hipStream_t stream) {
    const float* x = (const float*)d_in[0];
    const float* alpha = (const float*)d_in[1];
    const float* noise = (const float*)d_in[2];
    float* out = (float*)d_out;
    float* P = out;
    float* masked = out + (size_t)NROW * NROW;
    float* ws = (float*)d_ws;
    float* r = ws;
    float* knn = ws + NROW;
    float* scale = ws + 2 * NROW;
    unsigned short* Mb = (unsigned short*)(ws + 3 * NROW);  // 4096x128 bf16, 1 MB

    k_mask<<<NROW, 128, 0, stream>>>(x, alpha, noise, masked, Mb, r);
    k_dx<<<dim3(NROW / 128, NROW / 128), 256, 0, stream>>>(Mb, r, P);
    k_knn<<<NROW, 256, 0, stream>>>(P, knn);
    k_sigma<<<1, 1024, 0, stream>>>(knn, scale);
    k_norm<<<NROW, 256, 0, stream>>>(P, scale);
}

// Round 14
// 123.782 us; speedup vs baseline: 1.0403x; 1.0403x over previous
//
#include <hip/hip_runtime.h>
#include <math.h>

#define NROW 4096
#define NDIM 128
#define KNN 10
#define LDSS 136  // bf16 LDS row stride (128 + 8 pad -> 2-way banks, 16B aligned)

typedef __bf16 bf16x8 __attribute__((ext_vector_type(8)));
typedef unsigned short u16x8 __attribute__((ext_vector_type(8)));
typedef unsigned short u16x4 __attribute__((ext_vector_type(4)));
typedef float f32x4 __attribute__((ext_vector_type(4)));

__device__ inline unsigned short f2bf(float f) {  // RTNE f32->bf16
    unsigned int u = __float_as_uint(f);
    u += 0x7FFFu + ((u >> 16) & 1u);
    return (unsigned short)(u >> 16);
}
__device__ inline float bf2f(unsigned short u) {
    return __uint_as_float((unsigned)u << 16);
}

// Dx intermediate (bf16) lives in the tail half of each f32 P-row slot:
//   bf16 row i = (__bf16*)(P + i*NROW + NROW/2), 4096 bf16 = 8 KB.

// ---- Kernel 1: gate, masked = x*gate (f32 + bf16 copies), r = rowsum(m^2) ---
__global__ __launch_bounds__(128) void k_mask(const float* __restrict__ x,
                                              const float* __restrict__ alpha,
                                              const float* __restrict__ noise,
                                              float* __restrict__ masked,
                                              unsigned short* __restrict__ mb,
                                              float* __restrict__ r) {
    int row = blockIdx.x;
    int c = threadIdx.x;
    float g = alpha[c] + 0.5f * noise[c] + 0.5f;
    g = fminf(fmaxf(g, 0.0f), 1.0f);
    float m = x[row * NDIM + c] * g;
    masked[row * NDIM + c] = m;
    mb[row * NDIM + c] = f2bf(m);   // bf16 source for the MFMA GEMM, written ONCE
    float v = m * m;
#pragma unroll
    for (int o = 32; o > 0; o >>= 1) v += __shfl_down(v, o, 64);
    __shared__ float partial[2];
    if ((c & 63) == 0) partial[c >> 6] = v;
    __syncthreads();
    if (c == 0) r[row] = partial[0] + partial[1];
}

// ------- Kernel 2: Dx = r_i + r_j - 2*M M^T via bf16 MFMA, 8-wave version ----
// Same 128x128 tile and LDS (69.6 KB, 2 blocks/CU) but 512 threads / 8 waves:
// resident waves/CU 8 -> 16, acc per wave 4x4 -> 4x2 (32 VGPR). Serial
// stage->MFMA->epilogue chain now has 2x the waves to hide latency behind.
// Per-element arithmetic and store addresses bit-identical to the 4-wave form.
__global__ __launch_bounds__(512) void k_dx(const unsigned short* __restrict__ Mb,
                                            const float* __restrict__ r,
                                            float* __restrict__ P) {
    __shared__ __align__(16) __bf16 Asm[128 * LDSS];
    __shared__ __align__(16) __bf16 Bsm[128 * LDSS];
    int tid = threadIdx.x;
    int bx = blockIdx.x, by = blockIdx.y;

    {
        const unsigned short* Ap = Mb + (size_t)by * 128 * NDIM;
        const unsigned short* Bp = Mb + (size_t)bx * 128 * NDIM;
        int c = (tid & 15) * 8;
        int r0 = tid >> 4;  // 0..31
#pragma unroll
        for (int i = 0; i < 4; ++i) {
            int row = r0 + i * 32;
            *(uint4*)&Asm[row * LDSS + c] = *(const uint4*)(Ap + row * NDIM + c);
            *(uint4*)&Bsm[row * LDSS + c] = *(const uint4*)(Bp + row * NDIM + c);
        }
    }
    __syncthreads();

    int wave = tid >> 6, lane = tid & 63;
    int wr = wave >> 2, wc = wave & 3;   // 2 x 4 wave grid: 64-row x 32-col tiles
    int quad = lane >> 4, l15 = lane & 15;

    f32x4 acc[4][2];
#pragma unroll
    for (int i = 0; i < 4; ++i)
#pragma unroll
        for (int j = 0; j < 2; ++j) acc[i][j] = (f32x4)(0.0f);

#pragma unroll
    for (int kk = 0; kk < 128; kk += 32) {
        int ka = kk + quad * 8;
        bf16x8 af[4], bfr[2];
#pragma unroll
        for (int ti = 0; ti < 4; ++ti)
            af[ti] = *(const bf16x8*)&Asm[(wr * 64 + ti * 16 + l15) * LDSS + ka];
#pragma unroll
        for (int tj = 0; tj < 2; ++tj)
            bfr[tj] = *(const bf16x8*)&Bsm[(wc * 32 + tj * 16 + l15) * LDSS + ka];
#pragma unroll
        for (int ti = 0; ti < 4; ++ti)
#pragma unroll
            for (int tj = 0; tj < 2; ++tj)
                acc[ti][tj] = __builtin_amdgcn_mfma_f32_16x16x32_bf16(
                    af[ti], bfr[tj], acc[ti][tj], 0, 0, 0);
    }

    int gi_base = by * 128 + wr * 64;
    int gj_base = bx * 128 + wc * 32;
    float rrow[4][4], rcol[2];
#pragma unroll
    for (int ti = 0; ti < 4; ++ti)
#pragma unroll
        for (int rg = 0; rg < 4; ++rg)
            rrow[ti][rg] = r[gi_base + ti * 16 + quad * 4 + rg];
#pragma unroll
    for (int tj = 0; tj < 2; ++tj) rcol[tj] = r[gj_base + tj * 16 + l15];
#pragma unroll
    for (int ti = 0; ti < 4; ++ti)
#pragma unroll
        for (int rg = 0; rg < 4; ++rg) {
            int grow = gi_base + ti * 16 + quad * 4 + rg;
            __bf16* brow = (__bf16*)(P + (size_t)grow * NROW + NROW / 2);
#pragma unroll
            for (int tj = 0; tj < 2; ++tj) {
                int gcol = gj_base + tj * 16 + l15;
                float d = rrow[ti][rg] + rcol[tj] - 2.0f * acc[ti][tj][rg];
                ((unsigned short*)brow)[gcol] = f2bf(d);
            }
        }
}

// ------- Kernel 3: wave-per-row top-10 via med3 insertion (R10 best) ---------
__global__ __launch_bounds__(256) void k_knn(const float* __restrict__ P,
                                             float* __restrict__ knn) {
    int tid = threadIdx.x;
    int wave = tid >> 6, lane = tid & 63;
    int row = blockIdx.x * 4 + wave;
    const unsigned short* drow =
        (const unsigned short*)(P + (size_t)row * NROW + NROW / 2);

    u16x8 v8[8];
#pragma unroll
    for (int c = 0; c < 8; ++c)
        v8[c] = *(const u16x8*)(drow + (c * 64 + lane) * 8);

    float t[KNN];
#pragma unroll
    for (int j = 0; j < KNN; ++j) t[j] = INFINITY;

#pragma unroll
    for (int c = 0; c < 8; ++c) {
#pragma unroll
        for (int e = 0; e < 8; ++e) {
            float cv = bf2f(v8[c][e]);
            float t0n = fminf(t[0], cv);
#pragma unroll
            for (int j = KNN - 1; j >= 1; --j)
                t[j] = __builtin_amdgcn_fmed3f(cv, t[j - 1], t[j]);
            t[0] = t0n;
        }
    }

#pragma unroll
    for (int r = 0; r < KNN; ++r) {
        float m = t[0];
#pragma unroll
        for (int o = 1; o < 64; o <<= 1)
            m = fminf(m, __shfl_xor(m, o, 64));
        if (r == KNN - 1) {
            if (lane == 0) knn[row] = m;
        } else {
            unsigned long long mask = __ballot(t[0] == m);
            if (lane == (int)(__ffsll((unsigned long long)mask) - 1)) {
#pragma unroll
                for (int j = 0; j < KNN - 1; ++j) t[j] = t[j + 1];
                t[KNN - 1] = INFINITY;
            }
        }
    }
}

// -------- Kernel 4: median via radix select with DATA-ADAPTIVE shifts --------
__device__ inline unsigned fmap(float f) {
    unsigned b = __float_as_uint(f);
    return b ^ ((b >> 31) ? 0xFFFFFFFFu : 0x80000000u);
}
__device__ inline float funmap(unsigned u) {
    unsigned b = (u & 0x80000000u) ? (u ^ 0x80000000u) : ~u;
    return __uint_as_float(b);
}

__global__ __launch_bounds__(1024) void k_sigma(const float* __restrict__ knn,
                                                float* __restrict__ scale_out) {
    __shared__ unsigned keys[NROW];
    __shared__ unsigned hist[2048];
    __shared__ unsigned s_prefix, s_R;
    __shared__ unsigned red_lo[16], red_hi[16];
    __shared__ float red_f[16];
    __shared__ unsigned red_u[16];
    int tid = threadIdx.x;
    int lane = tid & 63, wid = tid >> 6;

    unsigned kmin = 0xFFFFFFFFu, kmax = 0u;
#pragma unroll
    for (int l = 0; l < 4; ++l) {
        unsigned k = fmap(knn[tid + l * 1024]);
        keys[tid + l * 1024] = k;
        kmin = min(kmin, k);
        kmax = max(kmax, k);
    }
#pragma unroll
    for (int o = 32; o > 0; o >>= 1) {
        kmin = min(kmin, (unsigned)__shfl_down(kmin, o, 64));
        kmax = max(kmax, (unsigned)__shfl_down(kmax, o, 64));
    }
    if (lane == 0) { red_lo[wid] = kmin; red_hi[wid] = kmax; }
    __syncthreads();
    kmin = red_lo[0]; kmax = red_hi[0];
#pragma unroll
    for (int w = 1; w < 16; ++w) {
        kmin = min(kmin, red_lo[w]);
        kmax = max(kmax, red_hi[w]);
    }

    unsigned xr = kmin ^ kmax;
    int B = (xr == 0u) ? 0 : (32 - __builtin_clz(xr));
    unsigned prefix0 = (B >= 32) ? 0u : (kmin >> B);

    if (tid == 0) { s_prefix = prefix0; s_R = 2047; }
    __syncthreads();

    int rem = B;
    for (int rd = 0; rd < 3; ++rd) {
        int w = rem > 11 ? 11 : rem;
        int sh = rem - w;
        unsigned nb = 1u << w;
        hist[tid] = 0;
        hist[tid + 1024] = 0;
        __syncthreads();
        unsigned prefix = s_prefix;
        unsigned R = s_R;
        int hsh = rem;
#pragma unroll
        for (int l = 0; l < 4; ++l) {
            unsigned k = keys[tid + l * 1024];
            bool match = (rd == 0) || ((k >> hsh) == prefix);
            if (match) atomicAdd(&hist[(k >> sh) & (nb - 1u)], 1u);
        }
        __syncthreads();
        if (tid < 64) {
            unsigned chunk = (nb >= 64u) ? (nb >> 6) : 1u;
            unsigned base = tid * chunk;
            unsigned lsum = 0;
            if (base < nb)
                for (unsigned i = 0; i < chunk; ++i) lsum += hist[base + i];
            unsigned pfx = lsum;
#pragma unroll
            for (int o = 1; o < 64; o <<= 1) {
                unsigned v = __shfl_up(pfx, o, 64);
                if (tid >= o) pfx += v;
            }
            unsigned excl = pfx - lsum;
            if (R >= excl && R < excl + lsum) {
                unsigned cum = excl;
                for (unsigned i = 0; i < chunk; ++i) {
                    unsigned h = hist[base + i];
                    if (R < cum + h) {
                        s_prefix = (prefix << w) | (base + i);
                        s_R = R - cum;
                        break;
                    }
                    cum += h;
                }
            }
        }
        __syncthreads();
        rem = sh;
    }

    unsigned mlk = s_prefix;
    unsigned cnt = 0, mng = 0xFFFFFFFFu;
#pragma unroll
    for (int l = 0; l < 4; ++l) {
        unsigned k = keys[tid + l * 1024];
        if (k <= mlk) cnt++;
        else mng = min(mng, k);
    }
#pragma unroll
    for (int o = 32; o > 0; o >>= 1) {
        cnt += __shfl_down(cnt, o, 64);
        mng = min(mng, (unsigned)__shfl_down(mng, o, 64));
    }
    if (lane == 0) { red_u[wid] = cnt; red_f[wid] = __uint_as_float(mng); }
    __syncthreads();
    if (tid == 0) {
        unsigned ctot = 0, m = 0xFFFFFFFFu;
        for (int w = 0; w < 16; ++w) {
            ctot += red_u[w];
            m = min(m, __float_as_uint(red_f[w]));
        }
        float ml = funmap(mlk);
        float mu = (ctot >= 2049u) ? ml : funmap(m);
        float sigma = 0.5f * (mu + ml);
        if (sigma < 1e-8f) sigma = 1.0f;
        scale_out[0] = -1.0f / (2.0f * sigma);
    }
}

// ------- Kernel 5: P-row = exp(bf16Dx*scale)/rowsum — LANE-COALESCED --------
__global__ __launch_bounds__(256) void k_norm(float* __restrict__ P,
                                              const float* __restrict__ scale_p) {
    int row = blockIdx.x, tid = threadIdx.x;
    float scale = scale_p[0];
    float* drow = P + (size_t)row * NROW;
    const unsigned short* brow = (const unsigned short*)(drow + NROW / 2);

    u16x4 a[4];
#pragma unroll
    for (int j = 0; j < 4; ++j)
        a[j] = *(const u16x4*)(brow + (j * 256 + tid) * 4);

    float v[16];
#pragma unroll
    for (int j = 0; j < 4; ++j)
#pragma unroll
        for (int e = 0; e < 4; ++e)
            v[j * 4 + e] = __expf(bf2f(a[j][e]) * scale);

    float sum = 0.0f;
#pragma unroll
    for (int e = 0; e < 16; ++e) sum += v[e];
#pragma unroll
    for (int o = 32; o > 0; o >>= 1) sum += __shfl_down(sum, o, 64);
    __shared__ float ps[4];
    int lane = tid & 63, wid = tid >> 6;
    if (lane == 0) ps[wid] = sum;
    __syncthreads();  // also orders all bf16 reads before the f32 overwrite
    float inv = 1.0f / (ps[0] + ps[1] + ps[2] + ps[3]);
#pragma unroll
    for (int j = 0; j < 4; ++j) {
        float4 o4;
        o4.x = v[j * 4 + 0] * inv;
        o4.y = v[j * 4 + 1] * inv;
        o4.z = v[j * 4 + 2] * inv;
        o4.w = v[j * 4 + 3] * inv;
        *(float4*)(drow + (j * 256 + tid) * 4) = o4;
    }
}

extern "C" void kernel_launch(void* const* d_in, const int* in_sizes, int n_in,
                              void* d_out, int out_size, void* d_ws, size_t ws_size,
                              hipStream_t stream) {
    const float* x = (const float*)d_in[0];
    const float* alpha = (const float*)d_in[1];
    const float* noise = (const float*)d_in[2];
    float* out = (float*)d_out;
    float* P = out;
    float* masked = out + (size_t)NROW * NROW;
    float* ws = (float*)d_ws;
    float* r = ws;
    float* knn = ws + NROW;
    float* scale = ws + 2 * NROW;
    unsigned short* Mb = (unsigned short*)(ws + 3 * NROW);  // 4096x128 bf16, 1 MB

    k_mask<<<NROW, 128, 0, stream>>>(x, alpha, noise, masked, Mb, r);
    k_dx<<<dim3(NROW / 128, NROW / 128), 512, 0, stream>>>(Mb, r, P);
    k_knn<<<NROW / 4, 256, 0, stream>>>(P, knn);
    k_sigma<<<1, 1024, 0, stream>>>(knn, scale);
    k_norm<<<NROW, 256, 0, stream>>>(P, scale);
}